// Round 8
// baseline (1208.910 us; speedup 1.0000x reference)
//
#include <hip/hip_runtime.h>

#define HID  64
#define SEQT 1024
#define NB   4

typedef _Float16 h8 __attribute__((ext_vector_type(8)));
typedef _Float16 h4 __attribute__((ext_vector_type(4)));
typedef float    f4 __attribute__((ext_vector_type(4)));

__device__ __forceinline__ float rcpf(float x){ return __builtin_amdgcn_rcpf(x); }
__device__ __forceinline__ float sigm(float x){ return rcpf(1.0f + __expf(-x)); }
__device__ __forceinline__ float tanh_fast(float x){
    // 1 - 2/(e^{2x}+1); correct saturation at +-inf
    return 1.0f - 2.0f * rcpf(__expf(2.0f * x) + 1.0f);
}

#define MFMA16(A,B,C) __builtin_amdgcn_mfma_f32_16x16x32_f16((A),(B),(C),0,0,0)

// split fp32 -> f16 hi + f16 lo (exact residual; 3-term product ~2^-24 rel)
__device__ __forceinline__ void split8(const float* __restrict__ p, h8& hi, h8& lo) {
    float4 u = *(const float4*)p;
    float4 v = *(const float4*)(p + 4);
    float vv[8] = {u.x, u.y, u.z, u.w, v.x, v.y, v.z, v.w};
    #pragma unroll
    for (int e = 0; e < 8; ++e) {
        _Float16 h = (_Float16)vv[e];
        hi[e] = h;
        lo[e] = (_Float16)(vv[e] - (float)h);
    }
}

// Block = 4 batches, 512 threads = 8 waves, 2 waves/SIMD.
//   waves 0-3 (L0): step t.  waves 4-7 (L1): step t-1 (1-iter lag pipeline).
// Wave wq owns UNITS [16*wq, 16*wq+16) for ALL 4 gate types: tiles q=0..3 at
// gate rows 64q+16wq. With the m89-verified D mapping (col=lane&15=batch,
// row=4*(lane>>4)+reg=unit-within-tile), each lane holds i/f/g/o of its own
// (unit,batch) IN REGISTERS -> cell update runs on MFMA accumulators, no
// G LDS round-trip, ONE barrier/iter. Each SIMD = one L0 wave (24 MFMA +
// cell) + one L1 wave (48 MFMA + cell): VALU/trans of one hides under the
// other's MFMA. Both roles share ONE A-frag array via pre-loop role pointers
// (uniform load code -> regalloc-safe, round-4 lesson; ~215 regs < 256).
// Race-freedom with 1 barrier: iter t reads h1 buf (t-1)&1, h2 buf t&1;
// writes h1 buf t&1, h2 buf (t+1)&1 -> read/write buffers always disjoint.
__global__ __launch_bounds__(512, 2)
void lstm2_fuse(const float* __restrict__ x,
                const float* __restrict__ W_ih0, const float* __restrict__ W_hh0,
                const float* __restrict__ b_ih0, const float* __restrict__ b_hh0,
                const float* __restrict__ W_ih1, const float* __restrict__ W_hh1,
                const float* __restrict__ b_ih1, const float* __restrict__ b_hh1,
                const float* __restrict__ fc1_w, const float* __restrict__ fc1_b,
                const float* __restrict__ fc2_w, const float* __restrict__ fc2_b,
                float* __restrict__ out, int nblk)
{
    const int blk = blockIdx.x;
    if (blk >= nblk) return;
    const int tid  = threadIdx.x;
    const int w    = tid >> 6;         // wave 0..7
    const int l    = tid & 63;
    const int wq   = w & 3;            // unit-block index (units 16*wq..+15)
    const bool isL0 = (w < 4);
    const int r16  = l & 15;           // A row in tile / D col (batch)
    const int g4   = l >> 4;           // k-subgroup / D row group
    const int cc   = r16 & 3;          // batch (cols replicated x4)
    const int B0   = blk * NB;

    // ---------------- LDS: h state double-buffered + final h2 ----------------
    __shared__ __align__(16) _Float16 h1h[2][NB][80], h1l[2][NB][80];
    __shared__ __align__(16) _Float16 h2h[2][NB][80], h2l[2][NB][80];
    __shared__ __align__(16) float h2f[NB][64];

    // ---------------- role pointers (pre-loop, wave-uniform) ----------------
    const float* WA  = isL0 ? W_hh0 : W_ih1;
    const float* WB  = isL0 ? W_hh0 : W_hh1;   // L0: duplicate (slots unused)
    const float* bip = isL0 ? b_ih0 : b_ih1;
    const float* bhp = isL0 ? b_hh0 : b_hh1;

    // ---------------- A-fragments: shared array, uniform load code ----------
    // aF[q][ks][hi/lo]: ks 0,1 from WA (K=64), ks 2,3 from WB (K=64)
    h8 aF[4][4][2];
    #pragma unroll
    for (int q = 0; q < 4; ++q) {
        const int row = 64 * q + 16 * wq + r16;
        #pragma unroll
        for (int ks = 0; ks < 2; ++ks) {
            split8(WA + row * HID + ks * 32 + g4 * 8, aF[q][ks][0],     aF[q][ks][1]);
            split8(WB + row * HID + ks * 32 + g4 * 8, aF[q][2 + ks][0], aF[q][2 + ks][1]);
        }
    }

    // ---------------- per-lane cell constants ----------------
    float biasv[16], wihv[16];
    #pragma unroll
    for (int q = 0; q < 4; ++q) {
        #pragma unroll
        for (int r = 0; r < 4; ++r) {
            const int grow = 64 * q + 16 * wq + 4 * g4 + r;
            biasv[4 * q + r] = bip[grow] + bhp[grow];
            wihv[4 * q + r]  = isL0 ? W_ih0[grow] : 0.0f;
        }
    }

    // ---------------- init ----------------
    if (tid < 320) {   // 320 ints per array = 2*4*80 halves
        ((int*)h1h)[tid] = 0; ((int*)h1l)[tid] = 0;
        ((int*)h2h)[tid] = 0; ((int*)h2l)[tid] = 0;
    }
    float cst[4] = {0.f, 0.f, 0.f, 0.f};
    float xc = 0.0f;                  // x chunk (L0 waves; 16 steps per refill)
    __syncthreads();

    const f4 z4 = {0.f, 0.f, 0.f, 0.f};

    #pragma unroll 1
    for (int t = 0; t <= SEQT; ++t) {
        const bool act = isL0 ? (t < SEQT) : (t >= 1);
        const int rb1 = (t + 1) & 1;   // buf holding h1(t-1)
        const int rb2 = t & 1;         // buf holding h2(t-2)
        if (act) {
            // x chunk refill: lane 4d+b holds x[b][t+d]; hidden under MFMA
            if (isL0 && (t & 15) == 0)
                xc = x[(size_t)(B0 + (l & 3)) * SEQT + t + (l >> 2)];

            // ---- B-fragments ----
            h8 b1h[2], b1l[2];
            #pragma unroll
            for (int ks = 0; ks < 2; ++ks) {
                b1h[ks] = *(const h8*)&h1h[rb1][cc][ks * 32 + g4 * 8];
                b1l[ks] = *(const h8*)&h1l[rb1][cc][ks * 32 + g4 * 8];
            }

            // ---- MFMA: 4 independent chains (tiles q = gate types) ----
            f4 acc[4];
            if (isL0) {                // G0(t) = Whh0 * h1(t-1): 6 per tile
                #pragma unroll
                for (int q = 0; q < 4; ++q) acc[q] = MFMA16(aF[q][0][0], b1h[0], z4);
                #pragma unroll
                for (int q = 0; q < 4; ++q) acc[q] = MFMA16(aF[q][0][1], b1h[0], acc[q]);
                #pragma unroll
                for (int q = 0; q < 4; ++q) acc[q] = MFMA16(aF[q][0][0], b1l[0], acc[q]);
                #pragma unroll
                for (int q = 0; q < 4; ++q) acc[q] = MFMA16(aF[q][1][0], b1h[1], acc[q]);
                #pragma unroll
                for (int q = 0; q < 4; ++q) acc[q] = MFMA16(aF[q][1][1], b1h[1], acc[q]);
                #pragma unroll
                for (int q = 0; q < 4; ++q) acc[q] = MFMA16(aF[q][1][0], b1l[1], acc[q]);
            } else {                   // G1(t-1) = Wih1*h1(t-1) + Whh1*h2(t-2)
                h8 b2h[2], b2l[2];
                #pragma unroll
                for (int ks = 0; ks < 2; ++ks) {
                    b2h[ks] = *(const h8*)&h2h[rb2][cc][ks * 32 + g4 * 8];
                    b2l[ks] = *(const h8*)&h2l[rb2][cc][ks * 32 + g4 * 8];
                }
                #pragma unroll
                for (int q = 0; q < 4; ++q) acc[q] = MFMA16(aF[q][0][0], b1h[0], z4);
                #pragma unroll
                for (int q = 0; q < 4; ++q) acc[q] = MFMA16(aF[q][0][1], b1h[0], acc[q]);
                #pragma unroll
                for (int q = 0; q < 4; ++q) acc[q] = MFMA16(aF[q][0][0], b1l[0], acc[q]);
                #pragma unroll
                for (int q = 0; q < 4; ++q) acc[q] = MFMA16(aF[q][1][0], b1h[1], acc[q]);
                #pragma unroll
                for (int q = 0; q < 4; ++q) acc[q] = MFMA16(aF[q][1][1], b1h[1], acc[q]);
                #pragma unroll
                for (int q = 0; q < 4; ++q) acc[q] = MFMA16(aF[q][1][0], b1l[1], acc[q]);
                #pragma unroll
                for (int q = 0; q < 4; ++q) acc[q] = MFMA16(aF[q][2][0], b2h[0], acc[q]);
                #pragma unroll
                for (int q = 0; q < 4; ++q) acc[q] = MFMA16(aF[q][2][1], b2h[0], acc[q]);
                #pragma unroll
                for (int q = 0; q < 4; ++q) acc[q] = MFMA16(aF[q][2][0], b2l[0], acc[q]);
                #pragma unroll
                for (int q = 0; q < 4; ++q) acc[q] = MFMA16(aF[q][3][0], b2h[1], acc[q]);
                #pragma unroll
                for (int q = 0; q < 4; ++q) acc[q] = MFMA16(aF[q][3][1], b2h[1], acc[q]);
                #pragma unroll
                for (int q = 0; q < 4; ++q) acc[q] = MFMA16(aF[q][3][0], b2l[1], acc[q]);
            }

            // ---- in-register cell: lane = (units 16wq+4g4+r, batch cc) ----
            const float xt = __shfl(xc, ((t & 15) << 2) | cc);   // L1: 0
            _Float16* ohp = isL0 ? &h1h[t & 1][0][0] : &h2h[(t + 1) & 1][0][0];
            _Float16* olp = isL0 ? &h1l[t & 1][0][0] : &h2l[(t + 1) & 1][0][0];
            h4 pH, pL; f4 hv;
            #pragma unroll
            for (int r = 0; r < 4; ++r) {
                float pi = acc[0][r] + fmaf(xt, wihv[r],      biasv[r]);
                float pf = acc[1][r] + fmaf(xt, wihv[4 + r],  biasv[4 + r]);
                float pg = acc[2][r] + fmaf(xt, wihv[8 + r],  biasv[8 + r]);
                float po = acc[3][r] + fmaf(xt, wihv[12 + r], biasv[12 + r]);
                float iv = sigm(pi), fv = sigm(pf);
                float gv = tanh_fast(pg), ov = sigm(po);
                cst[r] = fmaf(fv, cst[r], iv * gv);
                float h = ov * tanh_fast(cst[r]);
                _Float16 hh = (_Float16)h;
                pH[r] = hh;
                pL[r] = (_Float16)(h - (float)hh);
                hv[r] = h;
            }
            if (r16 < 4) {             // one replica group writes
                const int u0 = 16 * wq + 4 * g4;
                *(h4*)&ohp[cc * 80 + u0] = pH;
                *(h4*)&olp[cc * 80 + u0] = pL;
                if (!isL0 && t == SEQT)
                    *(f4*)&h2f[cc][u0] = hv;     // final h2, fp32
            }
        }
        __syncthreads();
    }

    // ---------------- FC head: wave w (<4) -> batch w ----------------
    if (w < 4) {
        float z = 0.0f;
        if (l < 32) {
            float acc = fc1_b[l];
            const f4* hvp = (const f4*)h2f[w];
            const f4* wvp = (const f4*)(fc1_w + l * HID);
            #pragma unroll
            for (int q = 0; q < 16; ++q) {
                f4 hq = hvp[q], wk = wvp[q];
                acc = fmaf(hq[0], wk[0], acc); acc = fmaf(hq[1], wk[1], acc);
                acc = fmaf(hq[2], wk[2], acc); acc = fmaf(hq[3], wk[3], acc);
            }
            z = fmaxf(acc, 0.0f) * fc2_w[l];
        }
        #pragma unroll
        for (int off = 32; off > 0; off >>= 1) z += __shfl_xor(z, off);
        if (l == 0) out[B0 + w] = z + fc2_b[0];
    }
}

extern "C" void kernel_launch(void* const* d_in, const int* in_sizes, int n_in,
                              void* d_out, int out_size, void* d_ws, size_t ws_size,
                              hipStream_t stream) {
    const float* x     = (const float*)d_in[0];
    const float* W_ih0 = (const float*)d_in[1];
    const float* W_hh0 = (const float*)d_in[2];
    const float* b_ih0 = (const float*)d_in[3];
    const float* b_hh0 = (const float*)d_in[4];
    const float* W_ih1 = (const float*)d_in[5];
    const float* W_hh1 = (const float*)d_in[6];
    const float* b_ih1 = (const float*)d_in[7];
    const float* b_hh1 = (const float*)d_in[8];
    const float* fc1_w = (const float*)d_in[9];
    const float* fc1_b = (const float*)d_in[10];
    const float* fc2_w = (const float*)d_in[11];
    const float* fc2_b = (const float*)d_in[12];
    float* out = (float*)d_out;

    const int batch = in_sizes[0] / SEQT;   // 1024
    const int nblk  = batch / NB;           // 256 blocks, 1 per CU
    dim3 grid(nblk), block(512);
    hipLaunchKernelGGL(lstm2_fuse, grid, block, 0, stream,
                       x, W_ih0, W_hh0, b_ih0, b_hh0,
                       W_ih1, W_hh1, b_ih1, b_hh1,
                       fc1_w, fc1_b, fc2_w, fc2_b, out, nblk);
}

// Round 9
// 1128.573 us; speedup vs baseline: 1.0712x; 1.0712x over previous
//
#include <hip/hip_runtime.h>

#define HID  64
#define SEQT 1024
#define NB   4

typedef _Float16 h8 __attribute__((ext_vector_type(8)));
typedef float    f4 __attribute__((ext_vector_type(4)));

__device__ __forceinline__ float rcpf(float x){ return __builtin_amdgcn_rcpf(x); }
__device__ __forceinline__ float sigm(float x){ return rcpf(1.0f + __expf(-x)); }
__device__ __forceinline__ float tanh_fast(float x){
    // 1 - 2/(e^{2x}+1); correct saturation at +-inf
    return 1.0f - 2.0f * rcpf(__expf(2.0f * x) + 1.0f);
}

#define MFMA16(A,B,C) __builtin_amdgcn_mfma_f32_16x16x32_f16((A),(B),(C),0,0,0)

// split fp32 -> f16 hi + f16 lo (exact residual; 3-term product ~2^-24 rel)
__device__ __forceinline__ void split8(const float* __restrict__ p, h8& hi, h8& lo) {
    float4 u = *(const float4*)p;
    float4 v = *(const float4*)(p + 4);
    float vv[8] = {u.x, u.y, u.z, u.w, v.x, v.y, v.z, v.w};
    #pragma unroll
    for (int e = 0; e < 8; ++e) {
        _Float16 h = (_Float16)vv[e];
        hi[e] = h;
        lo[e] = (_Float16)(vv[e] - (float)h);
    }
}

// Block = 4 batches, 512 threads = 8 waves (2/SIMD).
// MFMA phase: wave m owns M-tiles {2m,2m+1} (gate rows 32m..32m+31) for BOTH
// pipelined layers: L0 step t (6 MFMA/tile) + L1 step t-1 (12 MFMA/tile) = 36
// MFMA/wave/iter. Pre-activations go to LDS G0/G1 (round-7 path).
// Cell phase: waves 0-3 only, thread=(unit l, batch w) — each gate computed
// exactly ONCE (round 8 paid 4x VALU for replicated in-register cell).
// 2 waves/SIMD => one wave's VALU/LDS hides under the other's MFMA (m114).
// h1/h2 double-buffered: h1(s) in buf s&1, h2(s) in buf s&1; iter t reads
// h1[(t+1)&1], h2[t&1], writes h1[t&1], h2[(t+1)&1] -> always disjoint.
// x per-wave from global, double-prefetched with 63-iter slack (no LDS).
__global__ __launch_bounds__(512, 2)
void lstm2_v9(const float* __restrict__ x,
              const float* __restrict__ W_ih0, const float* __restrict__ W_hh0,
              const float* __restrict__ b_ih0, const float* __restrict__ b_hh0,
              const float* __restrict__ W_ih1, const float* __restrict__ W_hh1,
              const float* __restrict__ b_ih1, const float* __restrict__ b_hh1,
              const float* __restrict__ fc1_w, const float* __restrict__ fc1_b,
              const float* __restrict__ fc2_w, const float* __restrict__ fc2_b,
              float* __restrict__ out, int nblk)
{
    const int blk = blockIdx.x;
    if (blk >= nblk) return;
    const int tid = threadIdx.x;
    const int w   = tid >> 6;          // wave 0..7
    const int l   = tid & 63;          // lane
    const int r16 = l & 15;            // A row in tile / D col (batch)
    const int g4  = l >> 4;            // k-subgroup / D row group
    const int cc  = r16 & 3;           // batch col for B-frag broadcast
    const int cb  = w & 3;             // cell batch (valid for w<4)
    const int B0  = blk * NB;

    // ---------------- LDS ----------------
    __shared__ __align__(16) _Float16 h1h[2][NB][80], h1l[2][NB][80];
    __shared__ __align__(16) _Float16 h2h[2][NB][80], h2l[2][NB][80];
    __shared__ __align__(16) float G0[NB][260];
    __shared__ __align__(16) float G1[NB][260];
    __shared__ __align__(16) float h2f[NB][64];

    // ---------------- A-fragments: tiles 2w, 2w+1, hi/lo f16 ----------------
    h8 a0[2][2][2];   // [tile][ks][hi/lo]  W_hh0 rows 32w+16*tile+r16
    h8 a1[2][4][2];   // ks 0,1: W_ih1 ; ks 2,3: W_hh1
    #pragma unroll
    for (int tt = 0; tt < 2; ++tt) {
        const int row = 32 * w + 16 * tt + r16;
        #pragma unroll
        for (int ks = 0; ks < 2; ++ks) {
            split8(W_hh0 + row * HID + ks * 32 + g4 * 8, a0[tt][ks][0],     a0[tt][ks][1]);
            split8(W_ih1 + row * HID + ks * 32 + g4 * 8, a1[tt][ks][0],     a1[tt][ks][1]);
            split8(W_hh1 + row * HID + ks * 32 + g4 * 8, a1[tt][2 + ks][0], a1[tt][2 + ks][1]);
        }
    }

    // ---------------- cell constants (thread (l, cb); used by w<4) ----------
    float bias0v[4], bias1v[4], wih0v[4];
    #pragma unroll
    for (int q = 0; q < 4; ++q) {
        const int grow = l + 64 * q;
        bias0v[q] = b_ih0[grow] + b_hh0[grow];
        bias1v[q] = b_ih1[grow] + b_hh1[grow];
        wih0v[q]  = W_ih0[grow];
    }

    // ---------------- init ----------------
    if (tid < 320) {   // 320 ints = 2*NB*80 halves per array
        ((int*)h1h)[tid] = 0; ((int*)h1l)[tid] = 0;
        ((int*)h2h)[tid] = 0; ((int*)h2l)[tid] = 0;
    }
    const size_t xbase = (size_t)(B0 + cb) * SEQT;
    float xc  = x[xbase + l];          // chunk for t = 0..63 (lane = t offset)
    float xcn = 0.0f;
    float c1 = 0.0f, c2 = 0.0f;
    __syncthreads();

    const f4 z4 = {0.f, 0.f, 0.f, 0.f};

    // iter t: L0 emits step t (t<SEQT), L1 emits step t-1 (t>=1)
    #pragma unroll 1
    for (int t = 0; t <= SEQT; ++t) {
        const int rb1 = (t + 1) & 1;   // buf of h1(t-1)
        const int rb2 = t & 1;         // buf of h2(t-2)
        const int wb1 = t & 1;         // buf for h1(t)
        const int wb2 = (t + 1) & 1;   // buf for h2(t-1)

        if ((t & 63) == 0 && t + 64 < SEQT)       // 63-iter-slack prefetch
            xcn = x[xbase + t + 64 + l];

        // ---- shared B-fragments: h1(t-1) ----
        h8 b1h[2], b1l[2];
        #pragma unroll
        for (int ks = 0; ks < 2; ++ks) {
            b1h[ks] = *(const h8*)&h1h[rb1][cc][ks * 32 + g4 * 8];
            b1l[ks] = *(const h8*)&h1l[rb1][cc][ks * 32 + g4 * 8];
        }

        // ---- L0: G0(t) = Whh0 * h1(t-1), 2 tiles x 6 MFMA ----
        if (t < SEQT) {
            f4 acc[2];
            #pragma unroll
            for (int tt = 0; tt < 2; ++tt) acc[tt] = MFMA16(a0[tt][0][0], b1h[0], z4);
            #pragma unroll
            for (int tt = 0; tt < 2; ++tt) acc[tt] = MFMA16(a0[tt][0][1], b1h[0], acc[tt]);
            #pragma unroll
            for (int tt = 0; tt < 2; ++tt) acc[tt] = MFMA16(a0[tt][0][0], b1l[0], acc[tt]);
            #pragma unroll
            for (int tt = 0; tt < 2; ++tt) acc[tt] = MFMA16(a0[tt][1][0], b1h[1], acc[tt]);
            #pragma unroll
            for (int tt = 0; tt < 2; ++tt) acc[tt] = MFMA16(a0[tt][1][1], b1h[1], acc[tt]);
            #pragma unroll
            for (int tt = 0; tt < 2; ++tt) acc[tt] = MFMA16(a0[tt][1][0], b1l[1], acc[tt]);
            if (r16 < NB) {
                #pragma unroll
                for (int tt = 0; tt < 2; ++tt)
                    *(f4*)&G0[r16][32 * w + 16 * tt + 4 * g4] = acc[tt];
            }
        }

        // ---- L1: G1(t-1) = Wih1*h1(t-1) + Whh1*h2(t-2), 2 tiles x 12 ----
        if (t >= 1) {
            h8 b2h[2], b2l[2];
            #pragma unroll
            for (int ks = 0; ks < 2; ++ks) {
                b2h[ks] = *(const h8*)&h2h[rb2][cc][ks * 32 + g4 * 8];
                b2l[ks] = *(const h8*)&h2l[rb2][cc][ks * 32 + g4 * 8];
            }
            f4 acc[2];
            #pragma unroll
            for (int tt = 0; tt < 2; ++tt) acc[tt] = MFMA16(a1[tt][0][0], b1h[0], z4);
            #pragma unroll
            for (int tt = 0; tt < 2; ++tt) acc[tt] = MFMA16(a1[tt][0][1], b1h[0], acc[tt]);
            #pragma unroll
            for (int tt = 0; tt < 2; ++tt) acc[tt] = MFMA16(a1[tt][0][0], b1l[0], acc[tt]);
            #pragma unroll
            for (int tt = 0; tt < 2; ++tt) acc[tt] = MFMA16(a1[tt][1][0], b1h[1], acc[tt]);
            #pragma unroll
            for (int tt = 0; tt < 2; ++tt) acc[tt] = MFMA16(a1[tt][1][1], b1h[1], acc[tt]);
            #pragma unroll
            for (int tt = 0; tt < 2; ++tt) acc[tt] = MFMA16(a1[tt][1][0], b1l[1], acc[tt]);
            #pragma unroll
            for (int tt = 0; tt < 2; ++tt) acc[tt] = MFMA16(a1[tt][2][0], b2h[0], acc[tt]);
            #pragma unroll
            for (int tt = 0; tt < 2; ++tt) acc[tt] = MFMA16(a1[tt][2][1], b2h[0], acc[tt]);
            #pragma unroll
            for (int tt = 0; tt < 2; ++tt) acc[tt] = MFMA16(a1[tt][2][0], b2l[0], acc[tt]);
            #pragma unroll
            for (int tt = 0; tt < 2; ++tt) acc[tt] = MFMA16(a1[tt][3][0], b2h[1], acc[tt]);
            #pragma unroll
            for (int tt = 0; tt < 2; ++tt) acc[tt] = MFMA16(a1[tt][3][1], b2h[1], acc[tt]);
            #pragma unroll
            for (int tt = 0; tt < 2; ++tt) acc[tt] = MFMA16(a1[tt][3][0], b2l[1], acc[tt]);
            if (r16 < NB) {
                #pragma unroll
                for (int tt = 0; tt < 2; ++tt)
                    *(f4*)&G1[r16][32 * w + 16 * tt + 4 * g4] = acc[tt];
            }
        }
        __syncthreads();                          // G0(t), G1(t-1) ready

        // ---- cell phase: waves 0-3, thread (unit l, batch w), once each ----
        if (w < 4) {
            if (t < SEQT) {
                const float xt = __shfl(xc, t & 63);
                float pre[4];
                #pragma unroll
                for (int q = 0; q < 4; ++q)
                    pre[q] = G0[w][l + 64 * q] + fmaf(xt, wih0v[q], bias0v[q]);
                float iv = sigm(pre[0]), fv = sigm(pre[1]);
                float gv = tanh_fast(pre[2]), ov = sigm(pre[3]);
                c1 = fmaf(fv, c1, iv * gv);
                float h1 = ov * tanh_fast(c1);
                _Float16 hh = (_Float16)h1;
                h1h[wb1][w][l] = hh;
                h1l[wb1][w][l] = (_Float16)(h1 - (float)hh);
            }
            if (t >= 1) {
                float pre[4];
                #pragma unroll
                for (int q = 0; q < 4; ++q)
                    pre[q] = G1[w][l + 64 * q] + bias1v[q];
                float iv = sigm(pre[0]), fv = sigm(pre[1]);
                float gv = tanh_fast(pre[2]), ov = sigm(pre[3]);
                c2 = fmaf(fv, c2, iv * gv);
                float h2 = ov * tanh_fast(c2);
                _Float16 hh = (_Float16)h2;
                h2h[wb2][w][l] = hh;
                h2l[wb2][w][l] = (_Float16)(h2 - (float)hh);
                if (t == SEQT) h2f[w][l] = h2;
            }
        }
        if ((t & 63) == 63) xc = xcn;             // swap x chunk (all waves)
        __syncthreads();                          // h1(t), h2(t-1) ready
    }

    // ---------------- FC head: wave w (<4) -> batch w ----------------
    if (w < 4) {
        float z = 0.0f;
        if (l < 32) {
            float acc = fc1_b[l];
            const f4* hvp = (const f4*)h2f[w];
            const f4* wvp = (const f4*)(fc1_w + l * HID);
            #pragma unroll
            for (int q = 0; q < 16; ++q) {
                f4 hq = hvp[q], wk = wvp[q];
                acc = fmaf(hq[0], wk[0], acc); acc = fmaf(hq[1], wk[1], acc);
                acc = fmaf(hq[2], wk[2], acc); acc = fmaf(hq[3], wk[3], acc);
            }
            z = fmaxf(acc, 0.0f) * fc2_w[l];
        }
        #pragma unroll
        for (int off = 32; off > 0; off >>= 1) z += __shfl_xor(z, off);
        if (l == 0) out[B0 + w] = z + fc2_b[0];
    }
}

extern "C" void kernel_launch(void* const* d_in, const int* in_sizes, int n_in,
                              void* d_out, int out_size, void* d_ws, size_t ws_size,
                              hipStream_t stream) {
    const float* x     = (const float*)d_in[0];
    const float* W_ih0 = (const float*)d_in[1];
    const float* W_hh0 = (const float*)d_in[2];
    const float* b_ih0 = (const float*)d_in[3];
    const float* b_hh0 = (const float*)d_in[4];
    const float* W_ih1 = (const float*)d_in[5];
    const float* W_hh1 = (const float*)d_in[6];
    const float* b_ih1 = (const float*)d_in[7];
    const float* b_hh1 = (const float*)d_in[8];
    const float* fc1_w = (const float*)d_in[9];
    const float* fc1_b = (const float*)d_in[10];
    const float* fc2_w = (const float*)d_in[11];
    const float* fc2_b = (const float*)d_in[12];
    float* out = (float*)d_out;

    const int batch = in_sizes[0] / SEQT;   // 1024
    const int nblk  = batch / NB;           // 256 blocks, 1 per CU
    dim3 grid(nblk), block(512);
    hipLaunchKernelGGL(lstm2_v9, grid, block, 0, stream,
                       x, W_ih0, W_hh0, b_ih0, b_hh0,
                       W_ih1, W_hh1, b_ih1, b_hh1,
                       fc1_w, fc1_b, fc2_w, fc2_b, out, nblk);
}

// Round 10
// 1044.629 us; speedup vs baseline: 1.1573x; 1.0804x over previous
//
#include <hip/hip_runtime.h>

#define HID  64
#define SEQT 1024
#define NB   4

typedef _Float16 h8 __attribute__((ext_vector_type(8)));
typedef float    f4 __attribute__((ext_vector_type(4)));

__device__ __forceinline__ float rcpf(float x){ return __builtin_amdgcn_rcpf(x); }
__device__ __forceinline__ float sigm(float x){ return rcpf(1.0f + __expf(-x)); }
__device__ __forceinline__ float tanh_fast(float x){
    // 1 - 2/(e^{2x}+1); correct saturation at +-inf
    return 1.0f - 2.0f * rcpf(__expf(2.0f * x) + 1.0f);
}

#define MFMA16(A,B,C) __builtin_amdgcn_mfma_f32_16x16x32_f16((A),(B),(C),0,0,0)

// split fp32 -> f16 hi + f16 lo (exact residual; 3-term product ~2^-24 rel)
__device__ __forceinline__ void split8(const float* __restrict__ p, h8& hi, h8& lo) {
    float4 u = *(const float4*)p;
    float4 v = *(const float4*)(p + 4);
    float vv[8] = {u.x, u.y, u.z, u.w, v.x, v.y, v.z, v.w};
    #pragma unroll
    for (int e = 0; e < 8; ++e) {
        _Float16 h = (_Float16)vv[e];
        hi[e] = h;
        lo[e] = (_Float16)(vv[e] - (float)h);
    }
}

// Round-9 skeleton (8 waves, 2/SIMD; wave m owns M-tiles {2m,2m+1} of both
// pipelined layers; G via LDS; lean cell) with three latency fixes:
//  1. Accumulation chains split: L0 6-deep -> 4x3-deep, L1 12-deep -> 8x3-deep
//     (+ f4 adds of disjoint k-group partials). Dep-stall on the MFMA pipe
//     drops ~4x; 12 independent chains/wave keep it fed.
//  2. t-loop unrolled x2 (t=0,1 peeled; t=SEQT epilogue): buffer indices are
//     compile-time -> no per-iter buffer-select/address VALU. All ds_reads
//     issued before the first MFMA cluster.
//  3. Cell split: waves 0-3 run cell0 (batch w), waves 4-7 run cell1
//     (batch w-4): halves the serial cell span. s_setprio(1) around MFMA.
// Race-freedom unchanged: iter t reads h1[(t+1)&1], h2[t&1]; writes h1[t&1],
// h2[(t+1)&1] — always disjoint; 2 barriers/iter.
__global__ __launch_bounds__(512, 2)
void lstm2_v10(const float* __restrict__ x,
               const float* __restrict__ W_ih0, const float* __restrict__ W_hh0,
               const float* __restrict__ b_ih0, const float* __restrict__ b_hh0,
               const float* __restrict__ W_ih1, const float* __restrict__ W_hh1,
               const float* __restrict__ b_ih1, const float* __restrict__ b_hh1,
               const float* __restrict__ fc1_w, const float* __restrict__ fc1_b,
               const float* __restrict__ fc2_w, const float* __restrict__ fc2_b,
               float* __restrict__ out, int nblk)
{
    const int blk = blockIdx.x;
    if (blk >= nblk) return;
    const int tid = threadIdx.x;
    const int w   = tid >> 6;          // wave 0..7
    const int l   = tid & 63;          // lane
    const int r16 = l & 15;            // A row in tile / D col (batch)
    const int g4  = l >> 4;            // k-subgroup / D row group
    const int cc  = r16 & 3;           // batch col for B-frag broadcast
    const int cb  = w & 3;             // cell batch
    const int B0  = blk * NB;

    // ---------------- LDS ----------------
    __shared__ __align__(16) _Float16 h1h[2][NB][80], h1l[2][NB][80];
    __shared__ __align__(16) _Float16 h2h[2][NB][80], h2l[2][NB][80];
    __shared__ __align__(16) float G0[NB][260];
    __shared__ __align__(16) float G1[NB][260];
    __shared__ __align__(16) float h2f[NB][64];

    // ---------------- A-fragments: tiles 2w, 2w+1, hi/lo f16 ----------------
    h8 a0[2][2][2];   // [tile][ks][hi/lo]  W_hh0 rows 32w+16*tile+r16
    h8 a1[2][4][2];   // ks 0,1: W_ih1 ; ks 2,3: W_hh1
    #pragma unroll
    for (int tt = 0; tt < 2; ++tt) {
        const int row = 32 * w + 16 * tt + r16;
        #pragma unroll
        for (int ks = 0; ks < 2; ++ks) {
            split8(W_hh0 + row * HID + ks * 32 + g4 * 8, a0[tt][ks][0],     a0[tt][ks][1]);
            split8(W_ih1 + row * HID + ks * 32 + g4 * 8, a1[tt][ks][0],     a1[tt][ks][1]);
            split8(W_hh1 + row * HID + ks * 32 + g4 * 8, a1[tt][2 + ks][0], a1[tt][2 + ks][1]);
        }
    }

    // ---------------- cell constants: role-based (L0: waves 0-3) ----------
    const float* bip = (w < 4) ? b_ih0 : b_ih1;
    const float* bhp = (w < 4) ? b_hh0 : b_hh1;
    float biasv[4], wihv[4];
    #pragma unroll
    for (int q = 0; q < 4; ++q) {
        const int grow = l + 64 * q;
        biasv[q] = bip[grow] + bhp[grow];
        wihv[q]  = (w < 4) ? W_ih0[grow] : 0.0f;
    }

    // ---------------- init ----------------
    if (tid < 320) {   // 320 ints = 2*NB*80 halves per array
        ((int*)h1h)[tid] = 0; ((int*)h1l)[tid] = 0;
        ((int*)h2h)[tid] = 0; ((int*)h2l)[tid] = 0;
    }
    const size_t xbase = (size_t)(B0 + cb) * SEQT;
    float xc  = x[xbase + l];          // chunk for t = 0..63 (lane = t offset)
    float xcn = 0.0f;
    float cst = 0.0f;                  // c1 (waves 0-3) / c2 (waves 4-7)
    __syncthreads();

    const f4 z4 = {0.f, 0.f, 0.f, 0.f};

    // one pipelined iteration; RB/WB are compile-time at every call site
    auto step = [&](int t_, int RB1, int RB2, int WB1, int WB2,
                    bool L0A, bool L1A, bool FIN) {
        if (((t_ & 63) == 0) && (t_ + 64 < SEQT))
            xcn = x[xbase + t_ + 64 + l];

        // ---- all ds_reads up front (latency hides under L0 cluster) ----
        h8 b1h0 = *(const h8*)&h1h[RB1][cc][g4 * 8];
        h8 b1h1 = *(const h8*)&h1h[RB1][cc][32 + g4 * 8];
        h8 b1l0 = *(const h8*)&h1l[RB1][cc][g4 * 8];
        h8 b1l1 = *(const h8*)&h1l[RB1][cc][32 + g4 * 8];
        h8 b2h0, b2h1, b2l0, b2l1;
        if (L1A) {
            b2h0 = *(const h8*)&h2h[RB2][cc][g4 * 8];
            b2h1 = *(const h8*)&h2h[RB2][cc][32 + g4 * 8];
            b2l0 = *(const h8*)&h2l[RB2][cc][g4 * 8];
            b2l1 = *(const h8*)&h2l[RB2][cc][32 + g4 * 8];
        }

        __builtin_amdgcn_s_setprio(1);
        if (L0A) {   // G0(t) = Whh0 * h1(t-1): 4 chains, depth 3
            f4 e0 = MFMA16(a0[0][0][0], b1h0, z4);
            f4 e1 = MFMA16(a0[1][0][0], b1h0, z4);
            f4 o0 = MFMA16(a0[0][1][0], b1h1, z4);
            f4 o1 = MFMA16(a0[1][1][0], b1h1, z4);
            e0 = MFMA16(a0[0][0][1], b1h0, e0);
            e1 = MFMA16(a0[1][0][1], b1h0, e1);
            o0 = MFMA16(a0[0][1][1], b1h1, o0);
            o1 = MFMA16(a0[1][1][1], b1h1, o1);
            e0 = MFMA16(a0[0][0][0], b1l0, e0);
            e1 = MFMA16(a0[1][0][0], b1l0, e1);
            o0 = MFMA16(a0[0][1][0], b1l1, o0);
            o1 = MFMA16(a0[1][1][0], b1l1, o1);
            e0 = e0 + o0;  e1 = e1 + o1;
            if (r16 < NB) {
                *(f4*)&G0[r16][32 * w + 4 * g4]      = e0;
                *(f4*)&G0[r16][32 * w + 16 + 4 * g4] = e1;
            }
        }
        if (L1A) {   // G1(t-1) = Wih1*h1(t-1) + Whh1*h2(t-2): 8 chains, depth 3
            f4 p0 = MFMA16(a1[0][0][0], b1h0, z4);
            f4 p1 = MFMA16(a1[1][0][0], b1h0, z4);
            f4 q0 = MFMA16(a1[0][1][0], b1h1, z4);
            f4 q1 = MFMA16(a1[1][1][0], b1h1, z4);
            f4 r0 = MFMA16(a1[0][2][0], b2h0, z4);
            f4 r1 = MFMA16(a1[1][2][0], b2h0, z4);
            f4 s0 = MFMA16(a1[0][3][0], b2h1, z4);
            f4 s1 = MFMA16(a1[1][3][0], b2h1, z4);
            p0 = MFMA16(a1[0][0][1], b1h0, p0);
            p1 = MFMA16(a1[1][0][1], b1h0, p1);
            q0 = MFMA16(a1[0][1][1], b1h1, q0);
            q1 = MFMA16(a1[1][1][1], b1h1, q1);
            r0 = MFMA16(a1[0][2][1], b2h0, r0);
            r1 = MFMA16(a1[1][2][1], b2h0, r1);
            s0 = MFMA16(a1[0][3][1], b2h1, s0);
            s1 = MFMA16(a1[1][3][1], b2h1, s1);
            p0 = MFMA16(a1[0][0][0], b1l0, p0);
            p1 = MFMA16(a1[1][0][0], b1l0, p1);
            q0 = MFMA16(a1[0][1][0], b1l1, q0);
            q1 = MFMA16(a1[1][1][0], b1l1, q1);
            r0 = MFMA16(a1[0][2][0], b2l0, r0);
            r1 = MFMA16(a1[1][2][0], b2l0, r1);
            s0 = MFMA16(a1[0][3][0], b2l1, s0);
            s1 = MFMA16(a1[1][3][0], b2l1, s1);
            p0 = (p0 + q0) + (r0 + s0);
            p1 = (p1 + q1) + (r1 + s1);
            if (r16 < NB) {
                *(f4*)&G1[r16][32 * w + 4 * g4]      = p0;
                *(f4*)&G1[r16][32 * w + 16 + 4 * g4] = p1;
            }
        }
        __builtin_amdgcn_s_setprio(0);
        __syncthreads();                       // G0(t), G1(t-1) ready

        // ---- cell: waves 0-3 -> cell0(batch w); waves 4-7 -> cell1 ----
        if (w < 4) {
            if (L0A) {
                const float xt = __shfl(xc, t_ & 63);
                float pre0 = G0[w][l]       + fmaf(xt, wihv[0], biasv[0]);
                float pre1 = G0[w][l + 64]  + fmaf(xt, wihv[1], biasv[1]);
                float pre2 = G0[w][l + 128] + fmaf(xt, wihv[2], biasv[2]);
                float pre3 = G0[w][l + 192] + fmaf(xt, wihv[3], biasv[3]);
                float iv = sigm(pre0), fv = sigm(pre1);
                float gv = tanh_fast(pre2), ov = sigm(pre3);
                cst = fmaf(fv, cst, iv * gv);
                float hv = ov * tanh_fast(cst);
                _Float16 hh = (_Float16)hv;
                h1h[WB1][w][l] = hh;
                h1l[WB1][w][l] = (_Float16)(hv - (float)hh);
            }
        } else {
            if (L1A) {
                float pre0 = G1[cb][l]       + biasv[0];
                float pre1 = G1[cb][l + 64]  + biasv[1];
                float pre2 = G1[cb][l + 128] + biasv[2];
                float pre3 = G1[cb][l + 192] + biasv[3];
                float iv = sigm(pre0), fv = sigm(pre1);
                float gv = tanh_fast(pre2), ov = sigm(pre3);
                cst = fmaf(fv, cst, iv * gv);
                float hv = ov * tanh_fast(cst);
                _Float16 hh = (_Float16)hv;
                h2h[WB2][cb][l] = hh;
                h2l[WB2][cb][l] = (_Float16)(hv - (float)hh);
                if (FIN) h2f[cb][l] = hv;
            }
        }
        if ((t_ & 63) == 63) xc = xcn;
        __syncthreads();                       // h1(t), h2(t-1) ready
    };

    step(0, 1, 0, 0, 1, true,  false, false);
    step(1, 0, 1, 1, 0, true,  true,  false);
    #pragma unroll 1
    for (int t = 2; t < SEQT; t += 2) {
        step(t,     1, 0, 0, 1, true, true, false);
        step(t + 1, 0, 1, 1, 0, true, true, false);
    }
    step(SEQT, 1, 0, 0, 1, false, true, true);

    // ---------------- FC head: wave w (<4) -> batch w ----------------
    if (w < 4) {
        float z = 0.0f;
        if (l < 32) {
            float acc = fc1_b[l];
            const f4* hvp = (const f4*)h2f[w];
            const f4* wvp = (const f4*)(fc1_w + l * HID);
            #pragma unroll
            for (int q = 0; q < 16; ++q) {
                f4 hq = hvp[q], wk = wvp[q];
                acc = fmaf(hq[0], wk[0], acc); acc = fmaf(hq[1], wk[1], acc);
                acc = fmaf(hq[2], wk[2], acc); acc = fmaf(hq[3], wk[3], acc);
            }
            z = fmaxf(acc, 0.0f) * fc2_w[l];
        }
        #pragma unroll
        for (int off = 32; off > 0; off >>= 1) z += __shfl_xor(z, off);
        if (l == 0) out[B0 + w] = z + fc2_b[0];
    }
}

extern "C" void kernel_launch(void* const* d_in, const int* in_sizes, int n_in,
                              void* d_out, int out_size, void* d_ws, size_t ws_size,
                              hipStream_t stream) {
    const float* x     = (const float*)d_in[0];
    const float* W_ih0 = (const float*)d_in[1];
    const float* W_hh0 = (const float*)d_in[2];
    const float* b_ih0 = (const float*)d_in[3];
    const float* b_hh0 = (const float*)d_in[4];
    const float* W_ih1 = (const float*)d_in[5];
    const float* W_hh1 = (const float*)d_in[6];
    const float* b_ih1 = (const float*)d_in[7];
    const float* b_hh1 = (const float*)d_in[8];
    const float* fc1_w = (const float*)d_in[9];
    const float* fc1_b = (const float*)d_in[10];
    const float* fc2_w = (const float*)d_in[11];
    const float* fc2_b = (const float*)d_in[12];
    float* out = (float*)d_out;

    const int batch = in_sizes[0] / SEQT;   // 1024
    const int nblk  = batch / NB;           // 256 blocks, 1 per CU
    dim3 grid(nblk), block(512);
    hipLaunchKernelGGL(lstm2_v10, grid, block, 0, stream,
                       x, W_ih0, W_hh0, b_ih0, b_hh0,
                       W_ih1, W_hh1, b_ih1, b_hh1,
                       fc1_w, fc1_b, fc2_w, fc2_b, out, nblk);
}

// Round 11
// 969.613 us; speedup vs baseline: 1.2468x; 1.0774x over previous
//
#include <hip/hip_runtime.h>

#define HID  64
#define SEQT 1024
#define NB   4

typedef _Float16 h8 __attribute__((ext_vector_type(8)));
typedef float    f4 __attribute__((ext_vector_type(4)));
typedef float    v2f __attribute__((ext_vector_type(2)));

__device__ __forceinline__ float rcpf(float x){ return __builtin_amdgcn_rcpf(x); }
__device__ __forceinline__ float sigm(float x){ return rcpf(1.0f + __expf(-x)); }
__device__ __forceinline__ float tanh_fast(float x){
    // 1 - 2/(e^{2x}+1); correct saturation at +-inf
    return 1.0f - 2.0f * rcpf(__expf(2.0f * x) + 1.0f);
}
__device__ __forceinline__ v2f pkfma(v2f a, v2f b, v2f c){
    return __builtin_elementwise_fma(a, b, c);      // -> v_pk_fma_f32
}

#define MFMA16(A,B,C) __builtin_amdgcn_mfma_f32_16x16x32_f16((A),(B),(C),0,0,0)

// split fp32 -> f16 hi + f16 lo (exact residual; 3-term product ~2^-24 rel)
__device__ __forceinline__ void split8(const float* __restrict__ p, h8& hi, h8& lo) {
    float4 u = *(const float4*)p;
    float4 v = *(const float4*)(p + 4);
    float vv[8] = {u.x, u.y, u.z, u.w, v.x, v.y, v.z, v.w};
    #pragma unroll
    for (int e = 0; e < 8; ++e) {
        _Float16 h = (_Float16)vv[e];
        hi[e] = h;
        lo[e] = (_Float16)(vv[e] - (float)h);
    }
}

// Round-10 skeleton with the VALU sources removed:
//  * ALL k-group/term summation via MFMA C-chaining (L0: 2 chains depth 6,
//    L1: 2 chains depth 12) — zero f4 partial adds, zero AGPR add-shuffling.
//    C-dep chaining runs at full rate on CDNA (it's the GEMM K-loop pattern);
//    only A/B deps stall, and those rotate across 4+ chains per SIMD.
//  * Cell preact math packed into v_pk_fma_f32/pk-add on pre-packed v2f
//    bias/Wih constants.
// Structure otherwise identical: 8 waves (2/SIMD), wave m owns M-tiles
// {2m,2m+1} of both pipelined layers; G via LDS; cell0 on waves 0-3, cell1 on
// waves 4-7; peeled x2 unroll (compile-time buffer indices); 2 barriers/iter;
// 63-iter-slack x prefetch; s_setprio around MFMA clusters.
__global__ __launch_bounds__(512, 2)
void lstm2_v11(const float* __restrict__ x,
               const float* __restrict__ W_ih0, const float* __restrict__ W_hh0,
               const float* __restrict__ b_ih0, const float* __restrict__ b_hh0,
               const float* __restrict__ W_ih1, const float* __restrict__ W_hh1,
               const float* __restrict__ b_ih1, const float* __restrict__ b_hh1,
               const float* __restrict__ fc1_w, const float* __restrict__ fc1_b,
               const float* __restrict__ fc2_w, const float* __restrict__ fc2_b,
               float* __restrict__ out, int nblk)
{
    const int blk = blockIdx.x;
    if (blk >= nblk) return;
    const int tid = threadIdx.x;
    const int w   = tid >> 6;          // wave 0..7
    const int l   = tid & 63;          // lane
    const int r16 = l & 15;            // A row in tile / D col (batch)
    const int g4  = l >> 4;            // k-subgroup / D row group
    const int cc  = r16 & 3;           // batch col for B-frag broadcast
    const int cb  = w & 3;             // cell batch
    const int B0  = blk * NB;

    // ---------------- LDS ----------------
    __shared__ __align__(16) _Float16 h1h[2][NB][80], h1l[2][NB][80];
    __shared__ __align__(16) _Float16 h2h[2][NB][80], h2l[2][NB][80];
    __shared__ __align__(16) float G0[NB][260];
    __shared__ __align__(16) float G1[NB][260];
    __shared__ __align__(16) float h2f[NB][64];

    // ---------------- A-fragments: tiles 2w, 2w+1, hi/lo f16 ----------------
    h8 a0[2][2][2];   // [tile][ks][hi/lo]  W_hh0 rows 32w+16*tile+r16
    h8 a1[2][4][2];   // ks 0,1: W_ih1 ; ks 2,3: W_hh1
    #pragma unroll
    for (int tt = 0; tt < 2; ++tt) {
        const int row = 32 * w + 16 * tt + r16;
        #pragma unroll
        for (int ks = 0; ks < 2; ++ks) {
            split8(W_hh0 + row * HID + ks * 32 + g4 * 8, a0[tt][ks][0],     a0[tt][ks][1]);
            split8(W_ih1 + row * HID + ks * 32 + g4 * 8, a1[tt][ks][0],     a1[tt][ks][1]);
            split8(W_hh1 + row * HID + ks * 32 + g4 * 8, a1[tt][2 + ks][0], a1[tt][2 + ks][1]);
        }
    }

    // ---------------- cell constants, packed v2f (L0 role: waves 0-3) -------
    const float* bip = (w < 4) ? b_ih0 : b_ih1;
    const float* bhp = (w < 4) ? b_hh0 : b_hh1;
    v2f biasA, biasB, wihA, wihB;
    biasA.x = bip[l]       + bhp[l];
    biasA.y = bip[l + 64]  + bhp[l + 64];
    biasB.x = bip[l + 128] + bhp[l + 128];
    biasB.y = bip[l + 192] + bhp[l + 192];
    if (w < 4) {
        wihA.x = W_ih0[l];       wihA.y = W_ih0[l + 64];
        wihB.x = W_ih0[l + 128]; wihB.y = W_ih0[l + 192];
    } else {
        wihA = (v2f){0.f, 0.f};  wihB = (v2f){0.f, 0.f};
    }

    // ---------------- init ----------------
    if (tid < 320) {   // 320 ints = 2*NB*80 halves per array
        ((int*)h1h)[tid] = 0; ((int*)h1l)[tid] = 0;
        ((int*)h2h)[tid] = 0; ((int*)h2l)[tid] = 0;
    }
    const size_t xbase = (size_t)(B0 + cb) * SEQT;
    float xc  = x[xbase + l];          // chunk for t = 0..63 (lane = t offset)
    float xcn = 0.0f;
    float cst = 0.0f;                  // c1 (waves 0-3) / c2 (waves 4-7)
    __syncthreads();

    const f4 z4 = {0.f, 0.f, 0.f, 0.f};

    // one pipelined iteration; RB/WB compile-time at every call site
    auto step = [&](int t_, int RB1, int RB2, int WB1, int WB2,
                    bool L0A, bool L1A, bool FIN) {
        if (((t_ & 63) == 0) && (t_ + 64 < SEQT))
            xcn = x[xbase + t_ + 64 + l];

        // ---- all ds_reads up front ----
        h8 b1h0 = *(const h8*)&h1h[RB1][cc][g4 * 8];
        h8 b1h1 = *(const h8*)&h1h[RB1][cc][32 + g4 * 8];
        h8 b1l0 = *(const h8*)&h1l[RB1][cc][g4 * 8];
        h8 b1l1 = *(const h8*)&h1l[RB1][cc][32 + g4 * 8];
        h8 b2h0, b2h1, b2l0, b2l1;
        if (L1A) {
            b2h0 = *(const h8*)&h2h[RB2][cc][g4 * 8];
            b2h1 = *(const h8*)&h2h[RB2][cc][32 + g4 * 8];
            b2l0 = *(const h8*)&h2l[RB2][cc][g4 * 8];
            b2l1 = *(const h8*)&h2l[RB2][cc][32 + g4 * 8];
        }

        __builtin_amdgcn_s_setprio(1);
        if (L0A) {   // G0(t) = Whh0 * h1(t-1): 2 C-chains, depth 6, no adds
            f4 e0 = MFMA16(a0[0][0][0], b1h0, z4);
            f4 e1 = MFMA16(a0[1][0][0], b1h0, z4);
            e0 = MFMA16(a0[0][0][1], b1h0, e0);
            e1 = MFMA16(a0[1][0][1], b1h0, e1);
            e0 = MFMA16(a0[0][0][0], b1l0, e0);
            e1 = MFMA16(a0[1][0][0], b1l0, e1);
            e0 = MFMA16(a0[0][1][0], b1h1, e0);
            e1 = MFMA16(a0[1][1][0], b1h1, e1);
            e0 = MFMA16(a0[0][1][1], b1h1, e0);
            e1 = MFMA16(a0[1][1][1], b1h1, e1);
            e0 = MFMA16(a0[0][1][0], b1l1, e0);
            e1 = MFMA16(a0[1][1][0], b1l1, e1);
            if (r16 < NB) {
                *(f4*)&G0[r16][32 * w + 4 * g4]      = e0;
                *(f4*)&G0[r16][32 * w + 16 + 4 * g4] = e1;
            }
        }
        if (L1A) {   // G1(t-1) = Wih1*h1(t-1) + Whh1*h2(t-2): 2 C-chains, depth 12
            f4 p0 = MFMA16(a1[0][0][0], b1h0, z4);
            f4 p1 = MFMA16(a1[1][0][0], b1h0, z4);
            p0 = MFMA16(a1[0][0][1], b1h0, p0);
            p1 = MFMA16(a1[1][0][1], b1h0, p1);
            p0 = MFMA16(a1[0][0][0], b1l0, p0);
            p1 = MFMA16(a1[1][0][0], b1l0, p1);
            p0 = MFMA16(a1[0][1][0], b1h1, p0);
            p1 = MFMA16(a1[1][1][0], b1h1, p1);
            p0 = MFMA16(a1[0][1][1], b1h1, p0);
            p1 = MFMA16(a1[1][1][1], b1h1, p1);
            p0 = MFMA16(a1[0][1][0], b1l1, p0);
            p1 = MFMA16(a1[1][1][0], b1l1, p1);
            p0 = MFMA16(a1[0][2][0], b2h0, p0);
            p1 = MFMA16(a1[1][2][0], b2h0, p1);
            p0 = MFMA16(a1[0][2][1], b2h0, p0);
            p1 = MFMA16(a1[1][2][1], b2h0, p1);
            p0 = MFMA16(a1[0][2][0], b2l0, p0);
            p1 = MFMA16(a1[1][2][0], b2l0, p1);
            p0 = MFMA16(a1[0][3][0], b2h1, p0);
            p1 = MFMA16(a1[1][3][0], b2h1, p1);
            p0 = MFMA16(a1[0][3][1], b2h1, p0);
            p1 = MFMA16(a1[1][3][1], b2h1, p1);
            p0 = MFMA16(a1[0][3][0], b2l1, p0);
            p1 = MFMA16(a1[1][3][0], b2l1, p1);
            if (r16 < NB) {
                *(f4*)&G1[r16][32 * w + 4 * g4]      = p0;
                *(f4*)&G1[r16][32 * w + 16 + 4 * g4] = p1;
            }
        }
        __builtin_amdgcn_s_setprio(0);
        __syncthreads();                       // G0(t), G1(t-1) ready

        // ---- cell: waves 0-3 -> cell0(batch w); waves 4-7 -> cell1 ----
        if (w < 4) {
            if (L0A) {
                const float xt = __shfl(xc, t_ & 63);
                v2f xt2 = {xt, xt};
                v2f gA = {G0[w][l],       G0[w][l + 64]};
                v2f gB = {G0[w][l + 128], G0[w][l + 192]};
                v2f pA = gA + pkfma(xt2, wihA, biasA);
                v2f pB = gB + pkfma(xt2, wihB, biasB);
                float iv = sigm(pA.x), fv = sigm(pA.y);
                float gv = tanh_fast(pB.x), ov = sigm(pB.y);
                cst = fmaf(fv, cst, iv * gv);
                float hv = ov * tanh_fast(cst);
                _Float16 hh = (_Float16)hv;
                h1h[WB1][w][l] = hh;
                h1l[WB1][w][l] = (_Float16)(hv - (float)hh);
            }
        } else {
            if (L1A) {
                v2f gA = {G1[cb][l],       G1[cb][l + 64]};
                v2f gB = {G1[cb][l + 128], G1[cb][l + 192]};
                v2f pA = gA + biasA;
                v2f pB = gB + biasB;
                float iv = sigm(pA.x), fv = sigm(pA.y);
                float gv = tanh_fast(pB.x), ov = sigm(pB.y);
                cst = fmaf(fv, cst, iv * gv);
                float hv = ov * tanh_fast(cst);
                _Float16 hh = (_Float16)hv;
                h2h[WB2][cb][l] = hh;
                h2l[WB2][cb][l] = (_Float16)(hv - (float)hh);
                if (FIN) h2f[cb][l] = hv;
            }
        }
        if ((t_ & 63) == 63) xc = xcn;
        __syncthreads();                       // h1(t), h2(t-1) ready
    };

    step(0, 1, 0, 0, 1, true,  false, false);
    step(1, 0, 1, 1, 0, true,  true,  false);
    #pragma unroll 1
    for (int t = 2; t < SEQT; t += 2) {
        step(t,     1, 0, 0, 1, true, true, false);
        step(t + 1, 0, 1, 1, 0, true, true, false);
    }
    step(SEQT, 1, 0, 0, 1, false, true, true);

    // ---------------- FC head: wave w (<4) -> batch w ----------------
    if (w < 4) {
        float z = 0.0f;
        if (l < 32) {
            float acc = fc1_b[l];
            const f4* hvp = (const f4*)h2f[w];
            const f4* wvp = (const f4*)(fc1_w + l * HID);
            #pragma unroll
            for (int q = 0; q < 16; ++q) {
                f4 hq = hvp[q], wk = wvp[q];
                acc = fmaf(hq[0], wk[0], acc); acc = fmaf(hq[1], wk[1], acc);
                acc = fmaf(hq[2], wk[2], acc); acc = fmaf(hq[3], wk[3], acc);
            }
            z = fmaxf(acc, 0.0f) * fc2_w[l];
        }
        #pragma unroll
        for (int off = 32; off > 0; off >>= 1) z += __shfl_xor(z, off);
        if (l == 0) out[B0 + w] = z + fc2_b[0];
    }
}

extern "C" void kernel_launch(void* const* d_in, const int* in_sizes, int n_in,
                              void* d_out, int out_size, void* d_ws, size_t ws_size,
                              hipStream_t stream) {
    const float* x     = (const float*)d_in[0];
    const float* W_ih0 = (const float*)d_in[1];
    const float* W_hh0 = (const float*)d_in[2];
    const float* b_ih0 = (const float*)d_in[3];
    const float* b_hh0 = (const float*)d_in[4];
    const float* W_ih1 = (const float*)d_in[5];
    const float* W_hh1 = (const float*)d_in[6];
    const float* b_ih1 = (const float*)d_in[7];
    const float* b_hh1 = (const float*)d_in[8];
    const float* fc1_w = (const float*)d_in[9];
    const float* fc1_b = (const float*)d_in[10];
    const float* fc2_w = (const float*)d_in[11];
    const float* fc2_b = (const float*)d_in[12];
    float* out = (float*)d_out;

    const int batch = in_sizes[0] / SEQT;   // 1024
    const int nblk  = batch / NB;           // 256 blocks, 1 per CU
    dim3 grid(nblk), block(512);
    hipLaunchKernelGGL(lstm2_v11, grid, block, 0, stream,
                       x, W_ih0, W_hh0, b_ih0, b_hh0,
                       W_ih1, W_hh1, b_ih1, b_hh1,
                       fc1_w, fc1_b, fc2_w, fc2_b, out, nblk);
}